// Round 1
// baseline (1042.490 us; speedup 1.0000x reference)
//
#include <hip/hip_runtime.h>
#include <math.h>

#define NTOK 8192
#define DM 1024
#define NE 8
#define DF 4096
#define NASSIGN (NTOK*2)
#define MAXTILES 136

typedef short  s16x8 __attribute__((ext_vector_type(8)));
typedef float  f32x4 __attribute__((ext_vector_type(4)));

// ---------------- workspace layout (bytes) ----------------
#define OFF_XN      0ull                       // 8192*1024*2        = 16777216
#define OFF_W1T     16777216ull                // 8*4096*1024*2      = 67108864
#define OFF_W2T     83886080ull                // 8*1024*4096*2      = 67108864
#define OFF_H       150994944ull               // 16384*4096*2       = 134217728
#define OFF_PROBS   285212672ull               // 8192*8*4           = 262144
#define OFF_TOPI    285474816ull               // 8192*2*4           = 65536
#define OFF_TOPP    285540352ull               // 8192*2*4           = 65536
#define OFF_ROWTOK  285605888ull               // 16384*4            = 65536
#define OFF_ROWP    285671424ull               // 16384*4            = 65536
#define OFF_COUNTS  285736960ull               // 8*4
#define OFF_CURSORS 285736992ull               // 8*4
#define OFF_NTILES  285737024ull               // 4 (+pad)
#define OFF_TILES   285737088ull               // 136*16
#define WS_NEEDED   285739264ull

__device__ __forceinline__ unsigned short f2bf(float f) {
  unsigned u = __builtin_bit_cast(unsigned, f);
  u += 0x7fffu + ((u >> 16) & 1u);
  return (unsigned short)(u >> 16);
}

__device__ __forceinline__ void gload_lds16(const void* g, void* l) {
  __builtin_amdgcn_global_load_lds(
      (const __attribute__((address_space(1))) void*)g,
      (__attribute__((address_space(3))) void*)l, 16, 0, 0);
}

// ---------------- init: zero expert counts ----------------
__global__ void init_kernel(unsigned* counts) {
  if (threadIdx.x < NE) counts[threadIdx.x] = 0u;
}

// ---------------- sentinel if ws too small ----------------
__global__ void sentinel_kernel(float* out, int n) {
  for (int i = blockIdx.x * 256 + threadIdx.x; i < n; i += 2048 * 256)
    out[i] = -12345.0f;
}

// ---------------- fused LayerNorm + router ----------------
__global__ __launch_bounds__(256) void ln_router_kernel(
    const float* __restrict__ x, const float* __restrict__ gamma,
    const float* __restrict__ beta, const float* __restrict__ rw,
    const float* __restrict__ rb, unsigned short* __restrict__ xnb,
    float* __restrict__ probs, int* __restrict__ topi,
    float* __restrict__ topp, unsigned* __restrict__ counts) {
  const int tok = blockIdx.x;
  const int t = threadIdx.x;
  const int lane = t & 63, wave = t >> 6;

  float4 xv = *(const float4*)(x + (size_t)tok * DM + t * 4);
  float s = xv.x + xv.y + xv.z + xv.w;
  float q = xv.x * xv.x + xv.y * xv.y + xv.z * xv.z + xv.w * xv.w;
  for (int o = 32; o > 0; o >>= 1) {
    s += __shfl_down(s, o);
    q += __shfl_down(q, o);
  }
  __shared__ float red[16];
  if (lane == 0) { red[wave] = s; red[8 + wave] = q; }
  __syncthreads();
  float tot  = red[0] + red[1] + red[2] + red[3];
  float totq = red[8] + red[9] + red[10] + red[11];
  float mu = tot * (1.0f / DM);
  float var = totq * (1.0f / DM) - mu * mu;
  float rstd = rsqrtf(var + 1e-5f);

  float4 g = *(const float4*)(gamma + t * 4);
  float4 b = *(const float4*)(beta + t * 4);
  float xn[4];
  xn[0] = (xv.x - mu) * rstd * g.x + b.x;
  xn[1] = (xv.y - mu) * rstd * g.y + b.y;
  xn[2] = (xv.z - mu) * rstd * g.z + b.z;
  xn[3] = (xv.w - mu) * rstd * g.w + b.w;
  ushort4 pk = { f2bf(xn[0]), f2bf(xn[1]), f2bf(xn[2]), f2bf(xn[3]) };
  *(ushort4*)(xnb + (size_t)tok * DM + t * 4) = pk;

  // router logits: this thread owns rows t*4 .. t*4+3 of rw [1024][8]
  float a[8] = {0, 0, 0, 0, 0, 0, 0, 0};
  const float4* r4 = (const float4*)(rw + (size_t)t * 32);
#pragma unroll
  for (int j = 0; j < 4; ++j) {
    float4 lo = r4[j * 2], hi = r4[j * 2 + 1];
    a[0] += xn[j] * lo.x; a[1] += xn[j] * lo.y;
    a[2] += xn[j] * lo.z; a[3] += xn[j] * lo.w;
    a[4] += xn[j] * hi.x; a[5] += xn[j] * hi.y;
    a[6] += xn[j] * hi.z; a[7] += xn[j] * hi.w;
  }
#pragma unroll
  for (int e = 0; e < 8; ++e)
    for (int o = 32; o > 0; o >>= 1) a[e] += __shfl_down(a[e], o);
  __shared__ float lred[4][8];
  if (lane == 0) {
#pragma unroll
    for (int e = 0; e < 8; ++e) lred[wave][e] = a[e];
  }
  __syncthreads();
  if (t == 0) {
    float lg[8], mx = -1e30f;
#pragma unroll
    for (int e = 0; e < 8; ++e) {
      lg[e] = lred[0][e] + lred[1][e] + lred[2][e] + lred[3][e] + rb[e];
      mx = fmaxf(mx, lg[e]);
    }
    float ex[8], se = 0.f;
#pragma unroll
    for (int e = 0; e < 8; ++e) { ex[e] = expf(lg[e] - mx); se += ex[e]; }
    float inv = 1.f / se;
    float pr[8];
#pragma unroll
    for (int e = 0; e < 8; ++e) {
      pr[e] = ex[e] * inv;
      probs[tok * 8 + e] = pr[e];
    }
    int i0 = 0;
#pragma unroll
    for (int e = 1; e < 8; ++e) if (pr[e] > pr[i0]) i0 = e;
    int i1 = (i0 == 0) ? 1 : 0;
#pragma unroll
    for (int e = 0; e < 8; ++e)
      if (e != i0 && pr[e] > pr[i1]) i1 = e;
    float p0 = pr[i0], p1 = pr[i1], inv2 = 1.f / (p0 + p1);
    topi[tok * 2] = i0; topi[tok * 2 + 1] = i1;
    topp[tok * 2] = p0 * inv2; topp[tok * 2 + 1] = p1 * inv2;
    atomicAdd(&counts[i0], 1u);
    atomicAdd(&counts[i1], 1u);
  }
}

// ---------------- plan: offsets + tile descriptors ----------------
__global__ void plan_kernel(const unsigned* __restrict__ counts,
                            unsigned* __restrict__ cursors,
                            int4* __restrict__ tiles, int* __restrict__ ntiles) {
  if (threadIdx.x == 0 && blockIdx.x == 0) {
    unsigned o = 0; int nt = 0;
    for (int e = 0; e < NE; ++e) {
      cursors[e] = o;
      unsigned c = counts[e];
      for (unsigned st = 0; st < c; st += 128u) {
        unsigned nr = c - st; if (nr > 128u) nr = 128u;
        tiles[nt] = make_int4(e, (int)(o + st), (int)nr, 0);
        ++nt;
      }
      o += c;
    }
    *ntiles = nt;
  }
}

// ---------------- scatter tokens into expert row lists ----------------
__global__ __launch_bounds__(256) void scatter_kernel(
    const int* __restrict__ topi, const float* __restrict__ topp,
    unsigned* cursors, int* row_token, float* row_p) {
  int tok = blockIdx.x * 256 + threadIdx.x;
  if (tok >= NTOK) return;
#pragma unroll
  for (int k = 0; k < 2; ++k) {
    int e = topi[tok * 2 + k];
    unsigned pos = atomicAdd(&cursors[e], 1u);
    row_token[pos] = tok;
    row_p[pos] = topp[tok * 2 + k];
  }
}

// ---------------- aux loss ----------------
__global__ __launch_bounds__(256) void aux_kernel(const float* __restrict__ probs,
                                                  float* __restrict__ out_aux) {
  const int t = threadIdx.x;
  float a[8] = {0, 0, 0, 0, 0, 0, 0, 0};
  for (int tok = t; tok < NTOK; tok += 256) {
    const float4* p4 = (const float4*)(probs + (size_t)tok * 8);
    float4 lo = p4[0], hi = p4[1];
    a[0] += lo.x; a[1] += lo.y; a[2] += lo.z; a[3] += lo.w;
    a[4] += hi.x; a[5] += hi.y; a[6] += hi.z; a[7] += hi.w;
  }
  const int lane = t & 63, wave = t >> 6;
#pragma unroll
  for (int e = 0; e < 8; ++e)
    for (int o = 32; o > 0; o >>= 1) a[e] += __shfl_down(a[e], o);
  __shared__ float sh[4][8];
  if (lane == 0) {
#pragma unroll
    for (int e = 0; e < 8; ++e) sh[wave][e] = a[e];
  }
  __syncthreads();
  if (t == 0) {
    float aux = 0.f;
#pragma unroll
    for (int e = 0; e < 8; ++e) {
      float load = (sh[0][e] + sh[1][e] + sh[2][e] + sh[3][e]) * (1.f / NTOK);
      float d = load - 0.125f;
      aux += d * d;
    }
    out_aux[0] = aux;
  }
}

// ---------------- transpose + f32->bf16 cast: w[E][R][C] -> wt[E][C][R] ----------------
__global__ __launch_bounds__(256) void transpose_cast_kernel(
    const float* __restrict__ w, unsigned short* __restrict__ wt, int R, int C) {
  __shared__ float tile[32][33];
  const int e = blockIdx.z;
  const int c0 = blockIdx.x * 32, r0 = blockIdx.y * 32;
  const float* we = w + (size_t)e * R * C;
  unsigned short* wte = wt + (size_t)e * R * C;
  const int tx = threadIdx.x & 31, ty = threadIdx.x >> 5;
#pragma unroll
  for (int i = 0; i < 4; ++i) {
    int r = r0 + ty + i * 8;
    tile[ty + i * 8][tx] = we[(size_t)r * C + c0 + tx];
  }
  __syncthreads();
#pragma unroll
  for (int i = 0; i < 4; ++i) {
    int c = c0 + ty + i * 8;
    wte[(size_t)c * R + r0 + tx] = f2bf(tile[tx][ty + i * 8]);
  }
}

// ---------------- residual copy ----------------
__global__ __launch_bounds__(256) void residual_kernel(const float4* __restrict__ x4,
                                                       float4* __restrict__ o4) {
  for (int i = blockIdx.x * 256 + threadIdx.x; i < (NTOK * DM / 4); i += 2048 * 256)
    o4[i] = x4[i];
}

// ---------------- GEMM1: h = silu(xn[gather] @ w1 + b1), bf16 out ----------------
__global__ __launch_bounds__(256) void gemm1_kernel(
    const unsigned short* __restrict__ xnb,   // [8192][1024]
    const unsigned short* __restrict__ w1t,   // [E][4096][1024]  ([n][k])
    const float* __restrict__ b1,             // [E][4096]
    const int* __restrict__ row_token,
    unsigned short* __restrict__ h,           // [16384][4096]
    const int4* __restrict__ tiles, const int* __restrict__ ntiles_p) {
  const int tile = blockIdx.y;
  if (tile >= *ntiles_p) return;
  const int4 td = tiles[tile];
  const int e = td.x, row_start = td.y, nrows = td.z;
  const int n0 = blockIdx.x * 128;
  const unsigned short* B = w1t + (size_t)e * ((size_t)DF * DM);

  __shared__ unsigned short As[128 * 64];   // [row][k]
  __shared__ unsigned short Bs[128 * 64];   // [col][k]

  const int t = threadIdx.x;
  const int lane = t & 63, wave = t >> 6;
  const int wr = wave >> 1, wc = wave & 1;

  const unsigned short* asrc[4];
  const unsigned short* bsrc[4];
#pragma unroll
  for (int it = 0; it < 4; ++it) {
    int r = it * 32 + (t >> 3);
    int rc = r < nrows ? r : (nrows - 1);
    int tok = row_token[row_start + rc];
    asrc[it] = xnb + (size_t)tok * DM + (t & 7) * 8;
    int c = it * 32 + (t >> 3);
    bsrc[it] = B + (size_t)(n0 + c) * DM + (t & 7) * 8;
  }

  f32x4 acc[4][4];
#pragma unroll
  for (int i = 0; i < 4; ++i)
#pragma unroll
    for (int j = 0; j < 4; ++j) acc[i][j] = (f32x4){0.f, 0.f, 0.f, 0.f};

  for (int k0 = 0; k0 < DM; k0 += 64) {
    __syncthreads();
#pragma unroll
    for (int it = 0; it < 4; ++it) {
      gload_lds16(asrc[it] + k0, &As[it * 2048 + wave * 512]);
      gload_lds16(bsrc[it] + k0, &Bs[it * 2048 + wave * 512]);
    }
    __syncthreads();
#pragma unroll
    for (int ks = 0; ks < 2; ++ks) {
      const int kb = ks * 32 + (lane >> 4) * 8;
      s16x8 af[4], bfr[4];
#pragma unroll
      for (int mf = 0; mf < 4; ++mf)
        af[mf] = *(const s16x8*)&As[(wr * 64 + mf * 16 + (lane & 15)) * 64 + kb];
#pragma unroll
      for (int nf = 0; nf < 4; ++nf)
        bfr[nf] = *(const s16x8*)&Bs[(wc * 64 + nf * 16 + (lane & 15)) * 64 + kb];
#pragma unroll
      for (int mf = 0; mf < 4; ++mf)
#pragma unroll
        for (int nf = 0; nf < 4; ++nf)
          acc[mf][nf] = __builtin_amdgcn_mfma_f32_16x16x32_bf16(af[mf], bfr[nf],
                                                                acc[mf][nf], 0, 0, 0);
    }
  }

  const float* b1e = b1 + e * DF;
#pragma unroll
  for (int mf = 0; mf < 4; ++mf) {
    int rbase = wr * 64 + mf * 16 + ((lane >> 4) << 2);
#pragma unroll
    for (int nf = 0; nf < 4; ++nf) {
      int col = n0 + wc * 64 + nf * 16 + (lane & 15);
      float bias = b1e[col];
#pragma unroll
      for (int r = 0; r < 4; ++r) {
        int rl = rbase + r;
        if (rl < nrows) {
          float v = acc[mf][nf][r] + bias;
          float sv = v / (1.f + __expf(-v));
          h[(size_t)(row_start + rl) * DF + col] = f2bf(sv);
        }
      }
    }
  }
}

// ---------------- GEMM2: out[token] += p * (h @ w2 + b2) ----------------
__global__ __launch_bounds__(256) void gemm2_kernel(
    const unsigned short* __restrict__ h,     // [16384][4096]
    const unsigned short* __restrict__ w2t,   // [E][1024][4096]  ([n][k])
    const float* __restrict__ b2,             // [E][1024]
    const int* __restrict__ row_token, const float* __restrict__ row_p,
    const int4* __restrict__ tiles, const int* __restrict__ ntiles_p,
    float* __restrict__ out) {
  const int tile = blockIdx.y;
  if (tile >= *ntiles_p) return;
  const int4 td = tiles[tile];
  const int e = td.x, row_start = td.y, nrows = td.z;
  const int n0 = blockIdx.x * 128;
  const unsigned short* B = w2t + (size_t)e * ((size_t)DM * DF);

  __shared__ unsigned short As[128 * 64];
  __shared__ unsigned short Bs[128 * 64];

  const int t = threadIdx.x;
  const int lane = t & 63, wave = t >> 6;
  const int wr = wave >> 1, wc = wave & 1;

  const unsigned short* asrc[4];
  const unsigned short* bsrc[4];
#pragma unroll
  for (int it = 0; it < 4; ++it) {
    int r = it * 32 + (t >> 3);
    int rc = r < nrows ? r : (nrows - 1);
    asrc[it] = h + (size_t)(row_start + rc) * DF + (t & 7) * 8;
    int c = it * 32 + (t >> 3);
    bsrc[it] = B + (size_t)(n0 + c) * DF + (t & 7) * 8;
  }

  f32x4 acc[4][4];
#pragma unroll
  for (int i = 0; i < 4; ++i)
#pragma unroll
    for (int j = 0; j < 4; ++j) acc[i][j] = (f32x4){0.f, 0.f, 0.f, 0.f};

  for (int k0 = 0; k0 < DF; k0 += 64) {
    __syncthreads();
#pragma unroll
    for (int it = 0; it < 4; ++it) {
      gload_lds16(asrc[it] + k0, &As[it * 2048 + wave * 512]);
      gload_lds16(bsrc[it] + k0, &Bs[it * 2048 + wave * 512]);
    }
    __syncthreads();
#pragma unroll
    for (int ks = 0; ks < 2; ++ks) {
      const int kb = ks * 32 + (lane >> 4) * 8;
      s16x8 af[4], bfr[4];
#pragma unroll
      for (int mf = 0; mf < 4; ++mf)
        af[mf] = *(const s16x8*)&As[(wr * 64 + mf * 16 + (lane & 15)) * 64 + kb];
#pragma unroll
      for (int nf = 0; nf < 4; ++nf)
        bfr[nf] = *(const s16x8*)&Bs[(wc * 64 + nf * 16 + (lane & 15)) * 64 + kb];
#pragma unroll
      for (int mf = 0; mf < 4; ++mf)
#pragma unroll
        for (int nf = 0; nf < 4; ++nf)
          acc[mf][nf] = __builtin_amdgcn_mfma_f32_16x16x32_bf16(af[mf], bfr[nf],
                                                                acc[mf][nf], 0, 0, 0);
    }
  }

  const float* b2e = b2 + e * DM;
#pragma unroll
  for (int mf = 0; mf < 4; ++mf) {
    int rbase = wr * 64 + mf * 16 + ((lane >> 4) << 2);
    int tokr[4]; float prr[4];
#pragma unroll
    for (int r = 0; r < 4; ++r) {
      int rl = rbase + r;
      if (rl < nrows) {
        tokr[r] = row_token[row_start + rl];
        prr[r] = row_p[row_start + rl];
      } else {
        tokr[r] = -1; prr[r] = 0.f;
      }
    }
#pragma unroll
    for (int nf = 0; nf < 4; ++nf) {
      int col = n0 + wc * 64 + nf * 16 + (lane & 15);
      float bias = b2e[col];
#pragma unroll
      for (int r = 0; r < 4; ++r) {
        if (tokr[r] >= 0) {
          float v = prr[r] * (acc[mf][nf][r] + bias);
          atomicAdd(&out[(size_t)tokr[r] * DM + col], v);
        }
      }
    }
  }
}

// ---------------- launch ----------------
extern "C" void kernel_launch(void* const* d_in, const int* in_sizes, int n_in,
                              void* d_out, int out_size, void* d_ws, size_t ws_size,
                              hipStream_t stream) {
  const float* x     = (const float*)d_in[0];
  const float* gamma = (const float*)d_in[1];
  const float* beta  = (const float*)d_in[2];
  const float* rw    = (const float*)d_in[3];
  const float* rb    = (const float*)d_in[4];
  const float* w1    = (const float*)d_in[5];
  const float* b1    = (const float*)d_in[6];
  const float* w2    = (const float*)d_in[7];
  const float* b2    = (const float*)d_in[8];
  float* out = (float*)d_out;
  char* ws = (char*)d_ws;

  if (ws_size < WS_NEEDED) {
    sentinel_kernel<<<2048, 256, 0, stream>>>(out, out_size);
    return;
  }

  unsigned short* xnb = (unsigned short*)(ws + OFF_XN);
  unsigned short* w1t = (unsigned short*)(ws + OFF_W1T);
  unsigned short* w2t = (unsigned short*)(ws + OFF_W2T);
  unsigned short* h   = (unsigned short*)(ws + OFF_H);
  float* probs        = (float*)(ws + OFF_PROBS);
  int* topi           = (int*)(ws + OFF_TOPI);
  float* topp         = (float*)(ws + OFF_TOPP);
  int* row_token      = (int*)(ws + OFF_ROWTOK);
  float* row_p        = (float*)(ws + OFF_ROWP);
  unsigned* counts    = (unsigned*)(ws + OFF_COUNTS);
  unsigned* cursors   = (unsigned*)(ws + OFF_CURSORS);
  int* ntiles         = (int*)(ws + OFF_NTILES);
  int4* tiles         = (int4*)(ws + OFF_TILES);

  init_kernel<<<1, 64, 0, stream>>>(counts);
  ln_router_kernel<<<NTOK, 256, 0, stream>>>(x, gamma, beta, rw, rb, xnb, probs,
                                             topi, topp, counts);
  plan_kernel<<<1, 1, 0, stream>>>(counts, cursors, tiles, ntiles);
  scatter_kernel<<<NTOK / 256, 256, 0, stream>>>(topi, topp, cursors, row_token, row_p);
  aux_kernel<<<1, 256, 0, stream>>>(probs, out + (size_t)NTOK * DM);
  transpose_cast_kernel<<<dim3(DF / 32, DM / 32, NE), 256, 0, stream>>>(w1, w1t, DM, DF);
  transpose_cast_kernel<<<dim3(DM / 32, DF / 32, NE), 256, 0, stream>>>(w2, w2t, DF, DM);
  residual_kernel<<<2048, 256, 0, stream>>>((const float4*)x, (float4*)out);
  gemm1_kernel<<<dim3(DF / 128, MAXTILES), 256, 0, stream>>>(xnb, w1t, b1, row_token,
                                                             h, tiles, ntiles);
  gemm2_kernel<<<dim3(DM / 128, MAXTILES), 256, 0, stream>>>(h, w2t, b2, row_token,
                                                             row_p, tiles, ntiles, out);
}

// Round 2
// 1021.725 us; speedup vs baseline: 1.0203x; 1.0203x over previous
//
#include <hip/hip_runtime.h>
#include <math.h>

#define NTOK 8192
#define DM 1024
#define NE 8
#define DF 4096
#define MAXTILES 136

typedef short  s16x8 __attribute__((ext_vector_type(8)));
typedef float  f32x4 __attribute__((ext_vector_type(4)));

// ---------------- workspace layout (bytes) ----------------
#define OFF_XN      0ull                       // 8192*1024*2        = 16777216
#define OFF_W1T     16777216ull                // 8*4096*1024*2      = 67108864
#define OFF_W2T     83886080ull                // 8*1024*4096*2      = 67108864
#define OFF_H       150994944ull               // 16384*4096*2       = 134217728
#define OFF_PROBS   285212672ull               // 8192*8*4           = 262144
#define OFF_TOPI    285474816ull               // 8192*2*4           = 65536
#define OFF_TOPP    285540352ull               // 8192*2*4           = 65536
#define OFF_ROWTOK  285605888ull               // 16384*4            = 65536
#define OFF_ROWP    285671424ull               // 16384*4            = 65536
#define OFF_COUNTS  285736960ull               // 8*4
#define OFF_CURSORS 285736992ull               // 8*4
#define OFF_NTILES  285737024ull               // 4 (+pad)
#define OFF_TILES   285737088ull               // 136*16
#define WS_NEEDED   285739264ull

__device__ __forceinline__ unsigned short f2bf(float f) {
  unsigned u = __builtin_bit_cast(unsigned, f);
  u += 0x7fffu + ((u >> 16) & 1u);
  return (unsigned short)(u >> 16);
}

__device__ __forceinline__ void gload_lds16(const void* g, void* l) {
  __builtin_amdgcn_global_load_lds(
      (const __attribute__((address_space(1))) void*)g,
      (__attribute__((address_space(3))) void*)l, 16, 0, 0);
}

// ---------------- init: zero expert counts ----------------
__global__ void init_kernel(unsigned* counts) {
  if (threadIdx.x < NE) counts[threadIdx.x] = 0u;
}

// ---------------- sentinel if ws too small ----------------
__global__ void sentinel_kernel(float* out, int n) {
  for (int i = blockIdx.x * 256 + threadIdx.x; i < n; i += 2048 * 256)
    out[i] = -12345.0f;
}

// ---------------- fused LayerNorm + router ----------------
__global__ __launch_bounds__(256) void ln_router_kernel(
    const float* __restrict__ x, const float* __restrict__ gamma,
    const float* __restrict__ beta, const float* __restrict__ rw,
    const float* __restrict__ rb, unsigned short* __restrict__ xnb,
    float* __restrict__ probs, int* __restrict__ topi,
    float* __restrict__ topp, unsigned* __restrict__ counts) {
  const int tok = blockIdx.x;
  const int t = threadIdx.x;
  const int lane = t & 63, wave = t >> 6;

  float4 xv = *(const float4*)(x + (size_t)tok * DM + t * 4);
  float s = xv.x + xv.y + xv.z + xv.w;
  float q = xv.x * xv.x + xv.y * xv.y + xv.z * xv.z + xv.w * xv.w;
  for (int o = 32; o > 0; o >>= 1) {
    s += __shfl_down(s, o);
    q += __shfl_down(q, o);
  }
  __shared__ float red[16];
  if (lane == 0) { red[wave] = s; red[8 + wave] = q; }
  __syncthreads();
  float tot  = red[0] + red[1] + red[2] + red[3];
  float totq = red[8] + red[9] + red[10] + red[11];
  float mu = tot * (1.0f / DM);
  float var = totq * (1.0f / DM) - mu * mu;
  float rstd = rsqrtf(var + 1e-5f);

  float4 g = *(const float4*)(gamma + t * 4);
  float4 b = *(const float4*)(beta + t * 4);
  float xn[4];
  xn[0] = (xv.x - mu) * rstd * g.x + b.x;
  xn[1] = (xv.y - mu) * rstd * g.y + b.y;
  xn[2] = (xv.z - mu) * rstd * g.z + b.z;
  xn[3] = (xv.w - mu) * rstd * g.w + b.w;
  ushort4 pk = { f2bf(xn[0]), f2bf(xn[1]), f2bf(xn[2]), f2bf(xn[3]) };
  *(ushort4*)(xnb + (size_t)tok * DM + t * 4) = pk;

  // router logits: this thread owns rows t*4 .. t*4+3 of rw [1024][8]
  float a[8] = {0, 0, 0, 0, 0, 0, 0, 0};
  const float4* r4 = (const float4*)(rw + (size_t)t * 32);
#pragma unroll
  for (int j = 0; j < 4; ++j) {
    float4 lo = r4[j * 2], hi = r4[j * 2 + 1];
    a[0] += xn[j] * lo.x; a[1] += xn[j] * lo.y;
    a[2] += xn[j] * lo.z; a[3] += xn[j] * lo.w;
    a[4] += xn[j] * hi.x; a[5] += xn[j] * hi.y;
    a[6] += xn[j] * hi.z; a[7] += xn[j] * hi.w;
  }
#pragma unroll
  for (int e = 0; e < 8; ++e)
    for (int o = 32; o > 0; o >>= 1) a[e] += __shfl_down(a[e], o);
  __shared__ float lred[4][8];
  if (lane == 0) {
#pragma unroll
    for (int e = 0; e < 8; ++e) lred[wave][e] = a[e];
  }
  __syncthreads();
  if (t == 0) {
    float lg[8], mx = -1e30f;
#pragma unroll
    for (int e = 0; e < 8; ++e) {
      lg[e] = lred[0][e] + lred[1][e] + lred[2][e] + lred[3][e] + rb[e];
      mx = fmaxf(mx, lg[e]);
    }
    float ex[8], se = 0.f;
#pragma unroll
    for (int e = 0; e < 8; ++e) { ex[e] = expf(lg[e] - mx); se += ex[e]; }
    float inv = 1.f / se;
    float pr[8];
#pragma unroll
    for (int e = 0; e < 8; ++e) {
      pr[e] = ex[e] * inv;
      probs[tok * 8 + e] = pr[e];
    }
    int i0 = 0;
#pragma unroll
    for (int e = 1; e < 8; ++e) if (pr[e] > pr[i0]) i0 = e;
    int i1 = (i0 == 0) ? 1 : 0;
#pragma unroll
    for (int e = 0; e < 8; ++e)
      if (e != i0 && pr[e] > pr[i1]) i1 = e;
    float p0 = pr[i0], p1 = pr[i1], inv2 = 1.f / (p0 + p1);
    topi[tok * 2] = i0; topi[tok * 2 + 1] = i1;
    topp[tok * 2] = p0 * inv2; topp[tok * 2 + 1] = p1 * inv2;
    atomicAdd(&counts[i0], 1u);
    atomicAdd(&counts[i1], 1u);
  }
}

// ---------------- plan: offsets + tile descriptors ----------------
__global__ void plan_kernel(const unsigned* __restrict__ counts,
                            unsigned* __restrict__ cursors,
                            int4* __restrict__ tiles, int* __restrict__ ntiles) {
  if (threadIdx.x == 0 && blockIdx.x == 0) {
    unsigned o = 0; int nt = 0;
    for (int e = 0; e < NE; ++e) {
      cursors[e] = o;
      unsigned c = counts[e];
      for (unsigned st = 0; st < c; st += 128u) {
        unsigned nr = c - st; if (nr > 128u) nr = 128u;
        tiles[nt] = make_int4(e, (int)(o + st), (int)nr, 0);
        ++nt;
      }
      o += c;
    }
    *ntiles = nt;
  }
}

// ---------------- scatter tokens into expert row lists ----------------
__global__ __launch_bounds__(256) void scatter_kernel(
    const int* __restrict__ topi, const float* __restrict__ topp,
    unsigned* cursors, int* row_token, float* row_p) {
  int tok = blockIdx.x * 256 + threadIdx.x;
  if (tok >= NTOK) return;
#pragma unroll
  for (int k = 0; k < 2; ++k) {
    int e = topi[tok * 2 + k];
    unsigned pos = atomicAdd(&cursors[e], 1u);
    row_token[pos] = tok;
    row_p[pos] = topp[tok * 2 + k];
  }
}

// ---------------- aux loss ----------------
__global__ __launch_bounds__(256) void aux_kernel(const float* __restrict__ probs,
                                                  float* __restrict__ out_aux) {
  const int t = threadIdx.x;
  float a[8] = {0, 0, 0, 0, 0, 0, 0, 0};
  for (int tok = t; tok < NTOK; tok += 256) {
    const float4* p4 = (const float4*)(probs + (size_t)tok * 8);
    float4 lo = p4[0], hi = p4[1];
    a[0] += lo.x; a[1] += lo.y; a[2] += lo.z; a[3] += lo.w;
    a[4] += hi.x; a[5] += hi.y; a[6] += hi.z; a[7] += hi.w;
  }
  const int lane = t & 63, wave = t >> 6;
#pragma unroll
  for (int e = 0; e < 8; ++e)
    for (int o = 32; o > 0; o >>= 1) a[e] += __shfl_down(a[e], o);
  __shared__ float sh[4][8];
  if (lane == 0) {
#pragma unroll
    for (int e = 0; e < 8; ++e) sh[wave][e] = a[e];
  }
  __syncthreads();
  if (t == 0) {
    float aux = 0.f;
#pragma unroll
    for (int e = 0; e < 8; ++e) {
      float load = (sh[0][e] + sh[1][e] + sh[2][e] + sh[3][e]) * (1.f / NTOK);
      float d = load - 0.125f;
      aux += d * d;
    }
    out_aux[0] = aux;
  }
}

// ---------------- transpose + f32->bf16 cast: w[E][R][C] -> wt[E][C][R] ----------------
// 32x32 tile, vectorized: float4 reads, ushort4 writes.
__global__ __launch_bounds__(256) void transpose_cast_kernel(
    const float* __restrict__ w, unsigned short* __restrict__ wt, int R, int C) {
  __shared__ float tile[32][33];
  const int e = blockIdx.z;
  const int c0 = blockIdx.x * 32, r0 = blockIdx.y * 32;
  const float* we = w + (size_t)e * R * C;
  unsigned short* wte = wt + (size_t)e * R * C;
  const int t = threadIdx.x;
  {
    int r = t >> 3, c = (t & 7) * 4;
    float4 v = *(const float4*)(we + (size_t)(r0 + r) * C + c0 + c);
    tile[r][c] = v.x; tile[r][c + 1] = v.y; tile[r][c + 2] = v.z; tile[r][c + 3] = v.w;
  }
  __syncthreads();
  {
    int c = t >> 3, r = (t & 7) * 4;
    ushort4 o;
    o.x = f2bf(tile[r][c]); o.y = f2bf(tile[r + 1][c]);
    o.z = f2bf(tile[r + 2][c]); o.w = f2bf(tile[r + 3][c]);
    *(ushort4*)(wte + (size_t)(c0 + c) * R + r0 + r) = o;
  }
}

// ---------------- residual copy ----------------
__global__ __launch_bounds__(256) void residual_kernel(const float4* __restrict__ x4,
                                                       float4* __restrict__ o4) {
  for (int i = blockIdx.x * 256 + threadIdx.x; i < (NTOK * DM / 4); i += 2048 * 256)
    o4[i] = x4[i];
}

// =====================================================================
// GEMM structure (both): 128x128 tile, BK=64, 4 waves, 16x16x32 MFMA.
// T2: XOR-swizzled LDS (chunk' = chunk ^ (row&7)); since global_load_lds
//     writes lane-linear, the SOURCE chunk is pre-swizzled and the READ
//     slot applies the same involution (rule #21).
// T3-min: double-buffered LDS, STAGE(next) issued before COMPUTE(cur),
//     single __syncthreads() per K-step (drains vmcnt -> depth-1 pipe).
// =====================================================================

// ---------------- GEMM1: h = silu(xn[gather] @ w1 + b1), bf16 out ----------------
__global__ __launch_bounds__(256) void gemm1_kernel(
    const unsigned short* __restrict__ xnb,   // [8192][1024]
    const unsigned short* __restrict__ w1t,   // [E][4096][1024]  ([n][k])
    const float* __restrict__ b1,             // [E][4096]
    const int* __restrict__ row_token,
    unsigned short* __restrict__ h,           // [16384][4096]
    const int4* __restrict__ tiles, const int* __restrict__ ntiles_p) {
  const int tile = blockIdx.y;
  if (tile >= *ntiles_p) return;
  const int4 td = tiles[tile];
  const int e = td.x, row_start = td.y, nrows = td.z;
  const int n0 = blockIdx.x * 128;
  const unsigned short* B = w1t + (size_t)e * ((size_t)DF * DM);

  __shared__ unsigned short As[2][128 * 64];
  __shared__ unsigned short Bs[2][128 * 64];

  const int t = threadIdx.x;
  const int lane = t & 63, wave = t >> 6;
  const int wr = wave >> 1, wc = wave & 1;
  // pre-swizzled source chunk: slot (t&7) holds logical chunk (t&7)^(row&7)
  const int swz = (((t & 7) ^ ((t >> 3) & 7)) * 8);

  const unsigned short* asrc[4];
  const unsigned short* bsrc[4];
#pragma unroll
  for (int it = 0; it < 4; ++it) {
    int r = it * 32 + (t >> 3);
    int rc = r < nrows ? r : (nrows - 1);
    int tok = row_token[row_start + rc];
    asrc[it] = xnb + (size_t)tok * DM;
    bsrc[it] = B + (size_t)(n0 + r) * DM;
  }

  auto stage = [&](int buf, int k0) {
#pragma unroll
    for (int it = 0; it < 4; ++it) {
      gload_lds16(asrc[it] + k0 + swz, &As[buf][it * 2048 + wave * 512]);
      gload_lds16(bsrc[it] + k0 + swz, &Bs[buf][it * 2048 + wave * 512]);
    }
  };

  f32x4 acc[4][4];
#pragma unroll
  for (int i = 0; i < 4; ++i)
#pragma unroll
    for (int j = 0; j < 4; ++j) acc[i][j] = (f32x4){0.f, 0.f, 0.f, 0.f};

  stage(0, 0);
  __syncthreads();

  const int NK = DM / 64;
  for (int kt = 0; kt < NK; ++kt) {
    const int cur = kt & 1;
    if (kt + 1 < NK) stage(cur ^ 1, (kt + 1) * 64);
    const unsigned short* Ab = &As[cur][0];
    const unsigned short* Bb = &Bs[cur][0];
#pragma unroll
    for (int ks = 0; ks < 2; ++ks) {
      const int slot = (((ks * 4) + (lane >> 4)) ^ (lane & 7)) * 8;
      s16x8 af[4], bfr[4];
#pragma unroll
      for (int mf = 0; mf < 4; ++mf)
        af[mf] = *(const s16x8*)&Ab[(wr * 64 + mf * 16 + (lane & 15)) * 64 + slot];
#pragma unroll
      for (int nf = 0; nf < 4; ++nf)
        bfr[nf] = *(const s16x8*)&Bb[(wc * 64 + nf * 16 + (lane & 15)) * 64 + slot];
#pragma unroll
      for (int mf = 0; mf < 4; ++mf)
#pragma unroll
        for (int nf = 0; nf < 4; ++nf)
          acc[mf][nf] = __builtin_amdgcn_mfma_f32_16x16x32_bf16(af[mf], bfr[nf],
                                                                acc[mf][nf], 0, 0, 0);
    }
    __syncthreads();
  }

  const float* b1e = b1 + e * DF;
#pragma unroll
  for (int mf = 0; mf < 4; ++mf) {
    int rbase = wr * 64 + mf * 16 + ((lane >> 4) << 2);
#pragma unroll
    for (int nf = 0; nf < 4; ++nf) {
      int col = n0 + wc * 64 + nf * 16 + (lane & 15);
      float bias = b1e[col];
#pragma unroll
      for (int r = 0; r < 4; ++r) {
        int rl = rbase + r;
        if (rl < nrows) {
          float v = acc[mf][nf][r] + bias;
          float sv = v / (1.f + __expf(-v));
          h[(size_t)(row_start + rl) * DF + col] = f2bf(sv);
        }
      }
    }
  }
}

// ---------------- GEMM2: out[token] += p * (h @ w2 + b2) ----------------
__global__ __launch_bounds__(256) void gemm2_kernel(
    const unsigned short* __restrict__ h,     // [16384][4096]
    const unsigned short* __restrict__ w2t,   // [E][1024][4096]  ([n][k])
    const float* __restrict__ b2,             // [E][1024]
    const int* __restrict__ row_token, const float* __restrict__ row_p,
    const int4* __restrict__ tiles, const int* __restrict__ ntiles_p,
    float* __restrict__ out) {
  const int tile = blockIdx.y;
  if (tile >= *ntiles_p) return;
  const int4 td = tiles[tile];
  const int e = td.x, row_start = td.y, nrows = td.z;
  const int n0 = blockIdx.x * 128;
  const unsigned short* B = w2t + (size_t)e * ((size_t)DM * DF);

  __shared__ unsigned short As[2][128 * 64];
  __shared__ unsigned short Bs[2][128 * 64];

  const int t = threadIdx.x;
  const int lane = t & 63, wave = t >> 6;
  const int wr = wave >> 1, wc = wave & 1;
  const int swz = (((t & 7) ^ ((t >> 3) & 7)) * 8);

  const unsigned short* asrc[4];
  const unsigned short* bsrc[4];
#pragma unroll
  for (int it = 0; it < 4; ++it) {
    int r = it * 32 + (t >> 3);
    int rc = r < nrows ? r : (nrows - 1);
    asrc[it] = h + (size_t)(row_start + rc) * DF;
    bsrc[it] = B + (size_t)(n0 + r) * DF;
  }

  auto stage = [&](int buf, int k0) {
#pragma unroll
    for (int it = 0; it < 4; ++it) {
      gload_lds16(asrc[it] + k0 + swz, &As[buf][it * 2048 + wave * 512]);
      gload_lds16(bsrc[it] + k0 + swz, &Bs[buf][it * 2048 + wave * 512]);
    }
  };

  f32x4 acc[4][4];
#pragma unroll
  for (int i = 0; i < 4; ++i)
#pragma unroll
    for (int j = 0; j < 4; ++j) acc[i][j] = (f32x4){0.f, 0.f, 0.f, 0.f};

  stage(0, 0);
  __syncthreads();

  const int NK = DF / 64;
  for (int kt = 0; kt < NK; ++kt) {
    const int cur = kt & 1;
    if (kt + 1 < NK) stage(cur ^ 1, (kt + 1) * 64);
    const unsigned short* Ab = &As[cur][0];
    const unsigned short* Bb = &Bs[cur][0];
#pragma unroll
    for (int ks = 0; ks < 2; ++ks) {
      const int slot = (((ks * 4) + (lane >> 4)) ^ (lane & 7)) * 8;
      s16x8 af[4], bfr[4];
#pragma unroll
      for (int mf = 0; mf < 4; ++mf)
        af[mf] = *(const s16x8*)&Ab[(wr * 64 + mf * 16 + (lane & 15)) * 64 + slot];
#pragma unroll
      for (int nf = 0; nf < 4; ++nf)
        bfr[nf] = *(const s16x8*)&Bb[(wc * 64 + nf * 16 + (lane & 15)) * 64 + slot];
#pragma unroll
      for (int mf = 0; mf < 4; ++mf)
#pragma unroll
        for (int nf = 0; nf < 4; ++nf)
          acc[mf][nf] = __builtin_amdgcn_mfma_f32_16x16x32_bf16(af[mf], bfr[nf],
                                                                acc[mf][nf], 0, 0, 0);
    }
    __syncthreads();
  }

  const float* b2e = b2 + e * DM;
#pragma unroll
  for (int mf = 0; mf < 4; ++mf) {
    int rbase = wr * 64 + mf * 16 + ((lane >> 4) << 2);
    int tokr[4]; float prr[4];
#pragma unroll
    for (int r = 0; r < 4; ++r) {
      int rl = rbase + r;
      if (rl < nrows) {
        tokr[r] = row_token[row_start + rl];
        prr[r] = row_p[row_start + rl];
      } else {
        tokr[r] = -1; prr[r] = 0.f;
      }
    }
#pragma unroll
    for (int nf = 0; nf < 4; ++nf) {
      int col = n0 + wc * 64 + nf * 16 + (lane & 15);
      float bias = b2e[col];
#pragma unroll
      for (int r = 0; r < 4; ++r) {
        if (tokr[r] >= 0) {
          float v = prr[r] * (acc[mf][nf][r] + bias);
          atomicAdd(&out[(size_t)tokr[r] * DM + col], v);
        }
      }
    }
  }
}

// ---------------- launch ----------------
extern "C" void kernel_launch(void* const* d_in, const int* in_sizes, int n_in,
                              void* d_out, int out_size, void* d_ws, size_t ws_size,
                              hipStream_t stream) {
  const float* x     = (const float*)d_in[0];
  const float* gamma = (const float*)d_in[1];
  const float* beta  = (const float*)d_in[2];
  const float* rw    = (const float*)d_in[3];
  const float* rb    = (const float*)d_in[4];
  const float* w1    = (const float*)d_in[5];
  const float* b1    = (const float*)d_in[6];
  const float* w2    = (const float*)d_in[7];
  const float* b2    = (const float*)d_in[8];
  float* out = (float*)d_out;
  char* ws = (char*)d_ws;

  if (ws_size < WS_NEEDED) {
    sentinel_kernel<<<2048, 256, 0, stream>>>(out, out_size);
    return;
  }

  unsigned short* xnb = (unsigned short*)(ws + OFF_XN);
  unsigned short* w1t = (unsigned short*)(ws + OFF_W1T);
  unsigned short* w2t = (unsigned short*)(ws + OFF_W2T);
  unsigned short* h   = (unsigned short*)(ws + OFF_H);
  float* probs        = (float*)(ws + OFF_PROBS);
  int* topi           = (int*)(ws + OFF_TOPI);
  float* topp         = (float*)(ws + OFF_TOPP);
  int* row_token      = (int*)(ws + OFF_ROWTOK);
  float* row_p        = (float*)(ws + OFF_ROWP);
  unsigned* counts    = (unsigned*)(ws + OFF_COUNTS);
  unsigned* cursors   = (unsigned*)(ws + OFF_CURSORS);
  int* ntiles         = (int*)(ws + OFF_NTILES);
  int4* tiles         = (int4*)(ws + OFF_TILES);

  init_kernel<<<1, 64, 0, stream>>>(counts);
  ln_router_kernel<<<NTOK, 256, 0, stream>>>(x, gamma, beta, rw, rb, xnb, probs,
                                             topi, topp, counts);
  plan_kernel<<<1, 1, 0, stream>>>(counts, cursors, tiles, ntiles);
  scatter_kernel<<<NTOK / 256, 256, 0, stream>>>(topi, topp, cursors, row_token, row_p);
  aux_kernel<<<1, 256, 0, stream>>>(probs, out + (size_t)NTOK * DM);
  transpose_cast_kernel<<<dim3(DF / 32, DM / 32, NE), 256, 0, stream>>>(w1, w1t, DM, DF);
  transpose_cast_kernel<<<dim3(DM / 32, DF / 32, NE), 256, 0, stream>>>(w2, w2t, DF, DM);
  residual_kernel<<<2048, 256, 0, stream>>>((const float4*)x, (float4*)out);
  gemm1_kernel<<<dim3(DF / 128, MAXTILES), 256, 0, stream>>>(xnb, w1t, b1, row_token,
                                                             h, tiles, ntiles);
  gemm2_kernel<<<dim3(DM / 128, MAXTILES), 256, 0, stream>>>(h, w2t, b2, row_token,
                                                             row_p, tiles, ntiles, out);
}